// Round 15
// baseline (504.613 us; speedup 1.0000x reference)
//
#include <hip/hip_runtime.h>
#include <hip/hip_bf16.h>
#include <math.h>

#define LN_EPS 1e-5f
#define NEGS 0.2f

typedef short s8v __attribute__((ext_vector_type(8)));
typedef short s4v __attribute__((ext_vector_type(4)));
typedef float f4v __attribute__((ext_vector_type(4)));
typedef unsigned short ushort;

// ---- helpers ---------------------------------------------------------------
__device__ __forceinline__ float wredsum(float v) {
#pragma unroll
    for (int s = 32; s > 0; s >>= 1) v += __shfl_xor(v, s);
    return v;
}
// fp32 -> bf16 round-to-nearest-even (bit-magic: measured faster than
// __float2bfloat16 library path — R5 236us vs R8 282us on k_fused)
__device__ __forceinline__ ushort f2bf(float x) {
    unsigned int u = __float_as_uint(x);
    u += 0x7fffu + ((u >> 16) & 1u);
    return (ushort)(u >> 16);
}
__device__ __forceinline__ float bf2f(ushort u) {
    return __uint_as_float(((unsigned int)u) << 16);
}

// ---- K_prep: build pre-swizzled bf16 LDS images of We, Wl, Wr --------------
__global__ __launch_bounds__(256) void k_prep(const float* __restrict__ Weg,
                                              const float* __restrict__ Wlg,
                                              const float* __restrict__ Wrg,
                                              ushort* __restrict__ weTg,
                                              ushort* __restrict__ wlrTg) {
    int i = blockIdx.x * 256 + threadIdx.x;
    if (i >= 7680) return;
    int mat = i / 2560;  // 0: We, 1: Wl, 2: Wr
    int j = i - mat * 2560;
    int n = j >> 3, kb = j & 7;
    const float* W = (mat == 0) ? Weg : (mat == 1) ? Wlg : Wrg;
    s8v v;
#pragma unroll
    for (int k = 0; k < 8; k++) v[k] = (short)f2bf(W[(kb * 8 + k) * 320 + n]);
    int by = (n * 128 + kb * 16) ^ ((n & 7) << 4);
    ushort* dstp = (mat == 0) ? weTg : (wlrTg + (mat - 1) * 20480);
    *(s8v*)((char*)dstp + by) = v;
}

// ---- K0: histogram of dst --------------------------------------------------
__global__ void k_hist(const int* __restrict__ dst, int* __restrict__ cnt, int E) {
    int idx = blockIdx.x * blockDim.x + threadIdx.x;
    int stride = gridDim.x * blockDim.x;
    for (; idx < E; idx += stride) atomicAdd(&cnt[dst[idx]], 1);
}

// ---- K0b: 3-phase parallel scan of (cnt[i]+1) -------------------------------
__global__ __launch_bounds__(1024) void k_scanA(const int* __restrict__ cnt,
                                                int* __restrict__ bsum, int N) {
    __shared__ int ws[16];
    int tt = threadIdx.x, ln = tt & 63, wv = tt >> 6;
    int i = blockIdx.x * 1024 + tt;
    int v = (i < N) ? (cnt[i] + 1) : 0;
#pragma unroll
    for (int s = 32; s > 0; s >>= 1) v += __shfl_xor(v, s);
    if (ln == 0) ws[wv] = v;
    __syncthreads();
    if (tt == 0) {
        int s = 0;
#pragma unroll
        for (int k = 0; k < 16; k++) s += ws[k];
        bsum[blockIdx.x] = s;
    }
}
__global__ __launch_bounds__(64) void k_scanB(const int* __restrict__ bsum,
                                              int* __restrict__ bpre,
                                              int* __restrict__ roffN, int nb) {
    int ln = threadIdx.x;
    int v = (ln < nb) ? bsum[ln] : 0;
    int x = v;
#pragma unroll
    for (int off = 1; off < 64; off <<= 1) {
        int y = __shfl_up(x, off);
        if (ln >= off) x += y;
    }
    if (ln < nb) bpre[ln] = x - v;
    if (ln == 63) *roffN = x;
}
__global__ __launch_bounds__(1024) void k_scanC(const int* __restrict__ cnt,
                                                const int* __restrict__ bpre,
                                                int* __restrict__ roff,
                                                int* __restrict__ wpos, int N) {
    __shared__ int ws[16];
    int tt = threadIdx.x, ln = tt & 63, wv = tt >> 6;
    int i = blockIdx.x * 1024 + tt;
    int v = (i < N) ? (cnt[i] + 1) : 0;
    int x = v;
#pragma unroll
    for (int off = 1; off < 64; off <<= 1) {
        int y = __shfl_up(x, off);
        if (ln >= off) x += y;
    }
    if (ln == 63) ws[wv] = x;
    __syncthreads();
    if (wv == 0) {
        int wsv = (ln < 16) ? ws[ln] : 0;
        int xs = wsv;
#pragma unroll
        for (int off = 1; off < 16; off <<= 1) {
            int y = __shfl_up(xs, off);
            if (ln >= off) xs += y;
        }
        if (ln < 16) ws[ln] = xs - wsv;
    }
    __syncthreads();
    int excl = x - v + ws[wv] + bpre[blockIdx.x];
    if (i < N) { roff[i] = excl; wpos[i] = excl; }
}

// ---- K0c (fallback path): scatter edge metadata only -----------------------
__global__ void k_scatter(const int* __restrict__ src, const int* __restrict__ dst,
                          int* __restrict__ wpos, int* __restrict__ eidC,
                          int* __restrict__ srcC, int* __restrict__ dstC, int E) {
    int idx = blockIdx.x * blockDim.x + threadIdx.x;
    int stride = gridDim.x * blockDim.x;
    for (; idx < E; idx += stride) {
        int d = dst[idx];
        int p = atomicAdd(&wpos[d], 1);
        eidC[p] = idx;
        srcC[p] = src[idx];
        dstC[p] = d;
    }
}

// ---- K0c' (relbf path): scatter metadata + rel row -> relbf[slot] ----------
__global__ __launch_bounds__(256) void k_scatter2(const int* __restrict__ src,
                                                  const int* __restrict__ dst,
                                                  int* __restrict__ wpos,
                                                  int* __restrict__ srcC,
                                                  int* __restrict__ dstC,
                                                  const float* __restrict__ rel,
                                                  ushort* __restrict__ relbf, int E) {
    int t = threadIdx.x;
    int ln = t & 63, wv = t >> 6;
    int sub = ln >> 4, m = ln & 15;
    long long base = ((long long)blockIdx.x * 4 + wv) * 4;  // 4 edges/wave
    long long stride = (long long)gridDim.x * 16;
    for (long long e0 = base; e0 < E; e0 += stride) {
        long long e = e0 + sub;
        bool ok = e < E;
        long long ee = ok ? e : (long long)(E - 1);
        float4 v = *(const float4*)(rel + ee * 64 + m * 4);
        int p = 0;
        if (m == 0 && ok) {
            int d = dst[ee];
            p = atomicAdd(&wpos[d], 1);
            srcC[p] = src[ee];
            dstC[p] = d;
        }
        p = __shfl(p, sub * 16);
        if (ok) {
            s4v o;
            o[0] = (short)f2bf(v.x); o[1] = (short)f2bf(v.y);
            o[2] = (short)f2bf(v.z); o[3] = (short)f2bf(v.w);
            *(s4v*)(relbf + (long long)p * 64 + m * 4) = o;
        }
    }
}

// ---- K1' (relbf path): per-node mean from CONTIGUOUS relbf segment ---------
__global__ __launch_bounds__(256) void k_mean(const int* __restrict__ roff,
                                              ushort* __restrict__ relbf,
                                              int* __restrict__ srcC,
                                              int* __restrict__ dstC, int N) {
    int t = threadIdx.x, ln = t & 63, wv = t >> 6;
    int nw = gridDim.x * 4;
    for (int n = blockIdx.x * 4 + wv; n < N; n += nw) {
        int r0 = roff[n], r1 = roff[n + 1];
        int deg = r1 - r0 - 1;  // real edges (last slot = self)
        float s0 = 0.f, s1 = 0.f, s2 = 0.f, s3 = 0.f;
        int j = 0;
        for (; j + 4 <= deg; j += 4) {
            s0 += bf2f(relbf[(long long)(r0 + j) * 64 + ln]);
            s1 += bf2f(relbf[(long long)(r0 + j + 1) * 64 + ln]);
            s2 += bf2f(relbf[(long long)(r0 + j + 2) * 64 + ln]);
            s3 += bf2f(relbf[(long long)(r0 + j + 3) * 64 + ln]);
        }
        for (; j < deg; j++) s0 += bf2f(relbf[(long long)(r0 + j) * 64 + ln]);
        float s = (s0 + s1) + (s2 + s3);
        relbf[(long long)(r1 - 1) * 64 + ln] = f2bf(s / (float)(deg > 0 ? deg : 1));
        if (ln == 0) { srcC[r1 - 1] = n; dstC[r1 - 1] = n; }
    }
}

// ---- K1 (fallback path): loop_attr via CSR gather --------------------------
__global__ __launch_bounds__(256) void k_loopcsr(const int* __restrict__ eidC_ro,
                                                 const int* __restrict__ roff,
                                                 const float* __restrict__ rel,
                                                 float* __restrict__ loopat,
                                                 int* __restrict__ eidC,
                                                 int* __restrict__ srcC,
                                                 int* __restrict__ dstC, int N, int E) {
    int t = threadIdx.x, ln = t & 63, wv = t >> 6;
    int nw = gridDim.x * 4;
    for (int n = blockIdx.x * 4 + wv; n < N; n += nw) {
        int r0 = roff[n], r1 = roff[n + 1];
        int deg = r1 - r0 - 1;
        float s0 = 0.f, s1 = 0.f, s2 = 0.f, s3 = 0.f;
        int j = 0;
        for (; j + 4 <= deg; j += 4) {
            int e0 = eidC_ro[r0 + j], e1 = eidC_ro[r0 + j + 1];
            int e2 = eidC_ro[r0 + j + 2], e3 = eidC_ro[r0 + j + 3];
            s0 += rel[(long long)e0 * 64 + ln];
            s1 += rel[(long long)e1 * 64 + ln];
            s2 += rel[(long long)e2 * 64 + ln];
            s3 += rel[(long long)e3 * 64 + ln];
        }
        for (; j < deg; j++) s0 += rel[(long long)eidC_ro[r0 + j] * 64 + ln];
        float s = (s0 + s1) + (s2 + s3);
        loopat[(long long)n * 64 + ln] = s / (float)(deg > 0 ? deg : 1);
        if (ln == 0) {
            eidC[r1 - 1] = E + n;
            srcC[r1 - 1] = n;
            dstC[r1 - 1] = n;
        }
    }
}

// ---- K2: MFMA linear: xl = bf16(feat@Wl+bl), xr = bf16(feat@Wr+br) ---------
__global__ __launch_bounds__(512) void k_linC(const float* __restrict__ feat,
                                              const ushort* __restrict__ wlrTg,
                                              const float* __restrict__ blg,
                                              const float* __restrict__ brg,
                                              ushort* __restrict__ xlbf,
                                              ushort* __restrict__ xrbf, int N) {
    __shared__ __align__(16) ushort wT[2][64 * 320];  // 80 KB pre-swizzled image
    int t = threadIdx.x;
    {
        const s8v* wsrc = (const s8v*)wlrTg;
        s8v* wdst = (s8v*)&wT[0][0];
        for (int i = t; i < 5120; i += 512) wdst[i] = wsrc[i];  // coalesced copy
    }
    __syncthreads();

    int l = t & 63, wv = t >> 6;
    int g = l >> 4, m = l & 15;
    int wstride = gridDim.x * 128;
    for (int r0 = (blockIdx.x * 8 + wv) * 16; r0 < N; r0 += wstride) {
        s8v afr[2];
        {
            long long row = (r0 + m < N) ? (r0 + m) : (N - 1);
#pragma unroll
            for (int kh = 0; kh < 2; kh++) {
                const float* p = feat + row * 64 + kh * 32 + g * 8;
                float4 u0 = *(const float4*)(p);
                float4 u1 = *(const float4*)(p + 4);
                s8v a;
                a[0] = (short)f2bf(u0.x); a[1] = (short)f2bf(u0.y);
                a[2] = (short)f2bf(u0.z); a[3] = (short)f2bf(u0.w);
                a[4] = (short)f2bf(u1.x); a[5] = (short)f2bf(u1.y);
                a[6] = (short)f2bf(u1.z); a[7] = (short)f2bf(u1.w);
                afr[kh] = a;
            }
        }
#pragma unroll
        for (int mat = 0; mat < 2; mat++) {
            const float* bias = mat ? brg : blg;
            ushort* y = mat ? xrbf : xlbf;
            const char* wb = (const char*)&wT[mat][0];
#pragma unroll
            for (int h = 0; h < 5; h++) {
                f4v acc[4];
#pragma unroll
                for (int ct = 0; ct < 4; ct++) acc[ct] = (f4v)0.0f;
#pragma unroll
                for (int ct = 0; ct < 4; ct++) {
                    int n = h * 64 + ct * 16 + m;
                    int b0 = (n * 128 + 0 * 64 + g * 16) ^ ((n & 7) << 4);
                    int b1 = (n * 128 + 1 * 64 + g * 16) ^ ((n & 7) << 4);
                    s8v bf0 = *(const s8v*)(wb + b0);
                    s8v bf1 = *(const s8v*)(wb + b1);
                    acc[ct] = __builtin_amdgcn_mfma_f32_16x16x32_bf16(afr[0], bf0, acc[ct], 0, 0, 0);
                    acc[ct] = __builtin_amdgcn_mfma_f32_16x16x32_bf16(afr[1], bf1, acc[ct], 0, 0, 0);
                }
                float bv[4];
#pragma unroll
                for (int ct = 0; ct < 4; ct++) bv[ct] = bias[h * 64 + ct * 16 + m];
#pragma unroll
                for (int q = 0; q < 4; q++) {
                    int row = r0 + g * 4 + q;
                    if (row < N) {
                        s4v o;
#pragma unroll
                        for (int ct = 0; ct < 4; ct++) o[ct] = (short)f2bf(acc[ct][q] + bv[ct]);
                        *(s4v*)(y + (long long)row * 320 + h * 64 + m * 4) = o;
                    }
                }
            }
        }
    }
}

// ---- K3: fused em-MFMA + z=exp(logit), CSR slot order (no atomics) ---------
template <bool RELBF>
__global__ __launch_bounds__(512) void k_fused(
    const float* __restrict__ rel, const float* __restrict__ loopat,
    const ushort* __restrict__ relbf,
    const int* __restrict__ eidC, const int* __restrict__ srcC,
    const int* __restrict__ dstC,
    const ushort* __restrict__ xlbf, const ushort* __restrict__ xrbf,
    const ushort* __restrict__ weTg, const float* __restrict__ attg,
    float* __restrict__ zC, int E, int M) {
    __shared__ __align__(16) ushort weT[64 * 320];  // 40 KB pre-swizzled image
    int t = threadIdx.x;
    {
        const s8v* wsrc = (const s8v*)weTg;
        s8v* wdst = (s8v*)weT;
        for (int i = t; i < 2560; i += 512) wdst[i] = wsrc[i];  // coalesced copy
    }
    __syncthreads();

    int l = t & 63, wv = t >> 6;
    int g = l >> 4, m = l & 15;
    int r0 = (blockIdx.x * 8 + wv) * 16;
    if (r0 >= M) return;

    // A fragment: lane holds ea[slot = r0+m][k = kh*32 + g*8 + j]
    s8v afr[2];
    if constexpr (RELBF) {
        int slot = r0 + m;
        if (slot >= M) slot = M - 1;
        const ushort* p = relbf + (long long)slot * 64 + g * 8;
        afr[0] = *(const s8v*)(p);
        afr[1] = *(const s8v*)(p + 32);
    } else {
        int slot = r0 + m;
        if (slot >= M) slot = M - 1;
        int e = eidC[slot];
        const float* ap = (e < E) ? (rel + (long long)e * 64)
                                  : (loopat + (long long)(e - E) * 64);
#pragma unroll
        for (int kh = 0; kh < 2; kh++) {
            const float* p = ap + kh * 32 + g * 8;
            float4 u0 = *(const float4*)(p);
            float4 u1 = *(const float4*)(p + 4);
            s8v a;
            a[0] = (short)f2bf(u0.x); a[1] = (short)f2bf(u0.y);
            a[2] = (short)f2bf(u0.z); a[3] = (short)f2bf(u0.w);
            a[4] = (short)f2bf(u1.x); a[5] = (short)f2bf(u1.y);
            a[6] = (short)f2bf(u1.z); a[7] = (short)f2bf(u1.w);
            afr[kh] = a;
        }
    }

    // epilogue slots for this lane: r0 + g*4 + q
    const ushort* xptr[4];
    const ushort* rptr[4];
    bool vld[4];
    int sarr[4];
#pragma unroll
    for (int q = 0; q < 4; q++) {
        int slot = r0 + g * 4 + q;
        vld[q] = slot < M;
        int ss = vld[q] ? slot : (M - 1);
        sarr[q] = ss;
        int s = srcC[ss], d = dstC[ss];
        xptr[q] = xlbf + (long long)s * 320 + m * 4;
        rptr[q] = xrbf + (long long)d * 320 + m * 4;
    }

    // double-buffered per-head gathers (static indices via full unroll)
    s4v xb[2][4], rb[2][4];
    float attb[2][4];
#pragma unroll
    for (int q = 0; q < 4; q++) {
        xb[0][q] = *(const s4v*)(xptr[q]);
        rb[0][q] = *(const s4v*)(rptr[q]);
    }
#pragma unroll
    for (int ct = 0; ct < 4; ct++) attb[0][ct] = attg[ct * 16 + m];

#pragma unroll
    for (int h = 0; h < 5; h++) {
        if (h < 4) {
#pragma unroll
            for (int q = 0; q < 4; q++) {
                xb[(h + 1) & 1][q] = *(const s4v*)(xptr[q] + (h + 1) * 64);
                rb[(h + 1) & 1][q] = *(const s4v*)(rptr[q] + (h + 1) * 64);
            }
#pragma unroll
            for (int ct = 0; ct < 4; ct++)
                attb[(h + 1) & 1][ct] = attg[(h + 1) * 64 + ct * 16 + m];
        }

        f4v acc[4];
#pragma unroll
        for (int ct = 0; ct < 4; ct++) acc[ct] = (f4v)0.0f;
        __builtin_amdgcn_s_setprio(1);
#pragma unroll
        for (int ct = 0; ct < 4; ct++) {
            int n = h * 64 + ct * 16 + m;
            int b0 = (n * 128 + 0 * 64 + g * 16) ^ ((n & 7) << 4);
            int b1 = (n * 128 + 1 * 64 + g * 16) ^ ((n & 7) << 4);
            s8v bf0 = *(const s8v*)((const char*)weT + b0);
            s8v bf1 = *(const s8v*)((const char*)weT + b1);
            acc[ct] = __builtin_amdgcn_mfma_f32_16x16x32_bf16(afr[0], bf0, acc[ct], 0, 0, 0);
            acc[ct] = __builtin_amdgcn_mfma_f32_16x16x32_bf16(afr[1], bf1, acc[ct], 0, 0, 0);
        }
        __builtin_amdgcn_s_setprio(0);

#pragma unroll
        for (int q = 0; q < 4; q++) {
            float sum = 0.f;
#pragma unroll
            for (int ct = 0; ct < 4; ct++) {
                float v = acc[ct][q] + bf2f((ushort)xb[h & 1][q][ct])
                                     + bf2f((ushort)rb[h & 1][q][ct]);
                v = v > 0.f ? v : v * NEGS;
                sum = fmaf(v, attb[h & 1][ct], sum);
            }
            sum += __shfl_xor(sum, 1);
            sum += __shfl_xor(sum, 2);
            sum += __shfl_xor(sum, 4);
            sum += __shfl_xor(sum, 8);
            if (vld[q] && m == 0)
                zC[(long long)sarr[q] * 5 + h] = __expf(sum);  // logits small; no max-shift
        }
    }
}

// ---- K4: single-pass conv accumulation, 2-way slot-unrolled ----------------
__global__ __launch_bounds__(256) void k_agg(const float* __restrict__ zC,
                                             const int* __restrict__ srcC,
                                             const int* __restrict__ roff,
                                             const ushort* __restrict__ xlbf,
                                             float* __restrict__ conv, int N) {
    int t = threadIdx.x, ln = t & 63, wv = t >> 6;
    int sub = ln >> 4, m = ln & 15;
    int nw = gridDim.x * 4;
    for (int n = blockIdx.x * 4 + wv; n < N; n += nw) {
        int r0 = roff[n], r1 = roff[n + 1];
        int deg = r1 - r0;  // includes self slot
        float se[5] = {0.f, 0.f, 0.f, 0.f, 0.f};
        float accv[5][4];
#pragma unroll
        for (int h = 0; h < 5; h++)
#pragma unroll
            for (int j = 0; j < 4; j++) accv[h][j] = 0.f;
        int jj = sub;
        // two independent chains per iteration (latency hiding)
        for (; jj + 4 < deg; jj += 8) {
            int slotA = r0 + jj, slotB = r0 + jj + 4;
            int sA = srcC[slotA], sB = srcC[slotB];
            const ushort* xpA = xlbf + (long long)sA * 320 + m * 4;
            const ushort* xpB = xlbf + (long long)sB * 320 + m * 4;
            long long lbA = (long long)slotA * 5, lbB = (long long)slotB * 5;
#pragma unroll
            for (int h = 0; h < 5; h++) {
                float zA = zC[lbA + h], zB = zC[lbB + h];
                se[h] += zA + zB;
                s4v xvA = *(const s4v*)(xpA + h * 64);
                s4v xvB = *(const s4v*)(xpB + h * 64);
#pragma unroll
                for (int j = 0; j < 4; j++) {
                    accv[h][j] = fmaf(zA, bf2f((ushort)xvA[j]), accv[h][j]);
                    accv[h][j] = fmaf(zB, bf2f((ushort)xvB[j]), accv[h][j]);
                }
            }
        }
        if (jj < deg) {
            int slot = r0 + jj;
            int s = srcC[slot];
            const ushort* xp = xlbf + (long long)s * 320 + m * 4;
            long long lb = (long long)slot * 5;
#pragma unroll
            for (int h = 0; h < 5; h++) {
                float z = zC[lb + h];
                se[h] += z;
                s4v xv = *(const s4v*)(xp + h * 64);
#pragma unroll
                for (int j = 0; j < 4; j++)
                    accv[h][j] = fmaf(z, bf2f((ushort)xv[j]), accv[h][j]);
            }
        }
        // each z was added by all 16 m-lanes of its sub-group -> divide by 16
        float dh[5];
#pragma unroll
        for (int h = 0; h < 5; h++) dh[h] = 16.0f / wredsum(se[h]);
        float tot[4];
#pragma unroll
        for (int j = 0; j < 4; j++) {
            float v = 0.f;
#pragma unroll
            for (int h = 0; h < 5; h++) v = fmaf(accv[h][j], dh[h], v);
            v += __shfl_xor(v, 16);
            v += __shfl_xor(v, 32);
            tot[j] = v;
        }
        float v0 = __shfl(tot[0], m);
        float v1 = __shfl(tot[1], m);
        float v2 = __shfl(tot[2], m);
        float v3 = __shfl(tot[3], m);
        float outv = (sub == 0) ? v0 : (sub == 1) ? v1 : (sub == 2) ? v2 : v3;
        conv[(long long)n * 64 + ln] = outv * 0.2f;
    }
}

// ---- K5: residual + LN -> MFMA MLP(64->128->64) -> residual + LN -----------
__global__ __launch_bounds__(512) void k_mlp(const float* __restrict__ feat,
                                             const float* __restrict__ conv,
                                             const float* __restrict__ cbias,
                                             const float* __restrict__ lng,
                                             const float* __restrict__ lnb,
                                             const float* __restrict__ ln1g,
                                             const float* __restrict__ ln1b,
                                             const float* __restrict__ fcwg,
                                             const float* __restrict__ fcb,
                                             const float* __restrict__ fc1wg,
                                             const float* __restrict__ fc1b,
                                             float* __restrict__ out, int N) {
    __shared__ __align__(16) ushort w1T[64 * 128];
    __shared__ __align__(16) ushort w2T[64 * 128];
    __shared__ __align__(16) ushort tls[8][16 * 128];
    __shared__ __align__(16) ushort xnl[8][16 * 64];
    int t = threadIdx.x;
    for (int i = t; i < 8192; i += 512) {
        int k = i >> 7, n = i & 127;
        int by = (n * 128 + k * 2) ^ ((n & 7) << 4);
        w1T[by >> 1] = f2bf(fcwg[i]);
    }
    for (int i = t; i < 8192; i += 512) {
        int k = i >> 6, n = i & 63;
        int by = (n * 256 + k * 2) ^ ((n & 7) << 4);
        w2T[by >> 1] = f2bf(fc1wg[i]);
    }
    __syncthreads();
    int ln = t & 63, wv = t >> 6;
    int g = ln >> 4, m = ln & 15;
    char* tb = (char*)&tls[wv][0];
    char* xb = (char*)&xnl[wv][0];
    float fcbv[8];
#pragma unroll
    for (int ct = 0; ct < 8; ct++) fcbv[ct] = fcb[ct * 16 + m];
    float fc1bv[4], g1v[4], b1v[4];
#pragma unroll
    for (int ct = 0; ct < 4; ct++) {
        fc1bv[ct] = fc1b[ct * 16 + m];
        g1v[ct] = ln1g[ct * 16 + m];
        b1v[ct] = ln1b[ct * 16 + m];
    }
    int nblk = gridDim.x * 8;
    for (int nb0 = (blockIdx.x * 8 + wv) * 16; nb0 < N; nb0 += nblk * 16) {
        int node = nb0 + m;
        long long nd = (node < N) ? node : (N - 1);
        float xv[2][8];
#pragma unroll
        for (int kh = 0; kh < 2; kh++) {
            int c0 = kh * 32 + g * 8;
            const float* fp = feat + nd * 64 + c0;
            const float* cp = conv + nd * 64 + c0;
            float4 f0 = *(const float4*)fp, f1 = *(const float4*)(fp + 4);
            float4 q0 = *(const float4*)cp, q1 = *(const float4*)(cp + 4);
            float4 cb0 = *(const float4*)(cbias + c0), cb1 = *(const float4*)(cbias + c0 + 4);
            xv[kh][0] = f0.x + q0.x + cb0.x; xv[kh][1] = f0.y + q0.y + cb0.y;
            xv[kh][2] = f0.z + q0.z + cb0.z; xv[kh][3] = f0.w + q0.w + cb0.w;
            xv[kh][4] = f1.x + q1.x + cb1.x; xv[kh][5] = f1.y + q1.y + cb1.y;
            xv[kh][6] = f1.z + q1.z + cb1.z; xv[kh][7] = f1.w + q1.w + cb1.w;
        }
        float sm = 0.f;
#pragma unroll
        for (int kh = 0; kh < 2; kh++)
#pragma unroll
            for (int j = 0; j < 8; j++) sm += xv[kh][j];
        sm += __shfl_xor(sm, 16); sm += __shfl_xor(sm, 32);
        float mu = sm * (1.0f / 64.0f);
        float vr = 0.f;
#pragma unroll
        for (int kh = 0; kh < 2; kh++)
#pragma unroll
            for (int j = 0; j < 8; j++) {
                float dv = xv[kh][j] - mu;
                vr += dv * dv;
            }
        vr += __shfl_xor(vr, 16); vr += __shfl_xor(vr, 32);
        float rs = rsqrtf(vr * (1.0f / 64.0f) + LN_EPS);
        s8v af[2];
#pragma unroll
        for (int kh = 0; kh < 2; kh++) {
            int c0 = kh * 32 + g * 8;
            float4 g0 = *(const float4*)(lng + c0), g1 = *(const float4*)(lng + c0 + 4);
            float4 e0 = *(const float4*)(lnb + c0), e1 = *(const float4*)(lnb + c0 + 4);
            float gg[8] = {g0.x, g0.y, g0.z, g0.w, g1.x, g1.y, g1.z, g1.w};
            float bb[8] = {e0.x, e0.y, e0.z, e0.w, e1.x, e1.y, e1.z, e1.w};
#pragma unroll
            for (int j = 0; j < 8; j++)
                af[kh][j] = (short)f2bf((xv[kh][j] - mu) * rs * gg[j] + bb[j]);
            int by = (m * 128 + (kh * 32 + g * 8) * 2) ^ ((m & 7) << 4);
            *(s8v*)(xb + by) = af[kh];
        }
        f4v a1[8];
#pragma unroll
        for (int ct = 0; ct < 8; ct++) a1[ct] = (f4v)0.0f;
#pragma unroll
        for (int ct = 0; ct < 8; ct++) {
            int n1 = ct * 16 + m;
#pragma unroll
            for (int kh = 0; kh < 2; kh++) {
                int by = (n1 * 128 + (kh * 32 + g * 8) * 2) ^ ((n1 & 7) << 4);
                s8v bf = *(const s8v*)((const char*)w1T + by);
                a1[ct] = __builtin_amdgcn_mfma_f32_16x16x32_bf16(af[kh], bf, a1[ct], 0, 0, 0);
            }
        }
#pragma unroll
        for (int ct = 0; ct < 8; ct++)
#pragma unroll
            for (int q = 0; q < 4; q++) {
                int r = g * 4 + q, c = ct * 16 + m;
                int by = (r * 256 + c * 2) ^ ((r & 7) << 4);
                *(ushort*)(tb + by) = f2bf(a1[ct][q] + fcbv[ct]);
            }
        f4v a2[4];
#pragma unroll
        for (int ct = 0; ct < 4; ct++) a2[ct] = (f4v)0.0f;
#pragma unroll
        for (int kh2 = 0; kh2 < 4; kh2++) {
            int by = (m * 256 + (kh2 * 32 + g * 8) * 2) ^ ((m & 7) << 4);
            s8v a2f = *(const s8v*)(tb + by);
#pragma unroll
            for (int ct = 0; ct < 4; ct++) {
                int n2 = ct * 16 + m;
                int by2 = (n2 * 256 + (kh2 * 32 + g * 8) * 2) ^ ((n2 & 7) << 4);
                s8v bf = *(const s8v*)((const char*)w2T + by2);
                a2[ct] = __builtin_amdgcn_mfma_f32_16x16x32_bf16(a2f, bf, a2[ct], 0, 0, 0);
            }
        }
#pragma unroll
        for (int q = 0; q < 4; q++) {
            int r = g * 4 + q;
            float yv[4];
#pragma unroll
            for (int ct = 0; ct < 4; ct++) {
                int by = (r * 128 + (ct * 16 + m) * 2) ^ ((r & 7) << 4);
                yv[ct] = bf2f(*(const ushort*)(xb + by)) + a2[ct][q] + fc1bv[ct];
            }
            float sm2 = (yv[0] + yv[1]) + (yv[2] + yv[3]);
            sm2 += __shfl_xor(sm2, 1); sm2 += __shfl_xor(sm2, 2);
            sm2 += __shfl_xor(sm2, 4); sm2 += __shfl_xor(sm2, 8);
            float mu2 = sm2 * (1.0f / 64.0f);
            float vr2 = 0.f;
#pragma unroll
            for (int ct = 0; ct < 4; ct++) {
                float dv = yv[ct] - mu2;
                vr2 += dv * dv;
            }
            vr2 += __shfl_xor(vr2, 1); vr2 += __shfl_xor(vr2, 2);
            vr2 += __shfl_xor(vr2, 4); vr2 += __shfl_xor(vr2, 8);
            float rs2 = rsqrtf(vr2 * (1.0f / 64.0f) + LN_EPS);
            int rn = nb0 + r;
            if (rn < N) {
#pragma unroll
                for (int ct = 0; ct < 4; ct++)
                    out[(long long)rn * 64 + ct * 16 + m] =
                        (yv[ct] - mu2) * rs2 * g1v[ct] + b1v[ct];
            }
        }
    }
}

// ---- launch ----------------------------------------------------------------
extern "C" void kernel_launch(void* const* d_in, const int* in_sizes, int n_in,
                              void* d_out, int out_size, void* d_ws, size_t ws_size,
                              hipStream_t stream) {
    const float* feat = (const float*)d_in[0];
    const int* ei = (const int*)d_in[1];
    const float* rel = (const float*)d_in[2];
    const float* Wl = (const float*)d_in[3];
    const float* bl = (const float*)d_in[4];
    const float* Wr = (const float*)d_in[5];
    const float* br = (const float*)d_in[6];
    const float* We = (const float*)d_in[7];
    const float* att = (const float*)d_in[8];
    const float* cbias = (const float*)d_in[9];
    const float* lng = (const float*)d_in[10];
    const float* lnb = (const float*)d_in[11];
    const float* ln1g = (const float*)d_in[12];
    const float* ln1b = (const float*)d_in[13];
    const float* fcw = (const float*)d_in[14];
    const float* fcb = (const float*)d_in[15];
    const float* fc1w = (const float*)d_in[16];
    const float* fc1b = (const float*)d_in[17];
    float* out = (float*)d_out;

    int N = in_sizes[0] / 64;
    int E = in_sizes[1] / 2;
    int M = E + N;
    const int* src = ei;
    const int* dst = ei + E;
    int nb = (N + 1023) / 1024;

    char* wsb = (char*)d_ws;
    ushort* xlbf = (ushort*)wsb;            wsb += (size_t)N * 320 * 2;
    ushort* xrbf = (ushort*)wsb;            wsb += (size_t)N * 320 * 2;
    float* loopat = (float*)wsb;            wsb += (size_t)N * 64 * 4;
    float* conv = (float*)wsb;              wsb += (size_t)N * 64 * 4;
    ushort* weTg = (ushort*)wsb;            wsb += 40960;
    ushort* wlrTg = (ushort*)wsb;           wsb += 81920;
    float* zC = (float*)wsb;                wsb += (size_t)M * 5 * 4;
    int* cnt = (int*)wsb;                   wsb += (size_t)N * 4;
    int* roff = (int*)wsb;                  wsb += (size_t)(N + 1) * 4;
    int* wpos = (int*)wsb;                  wsb += (size_t)N * 4;
    int* eidC = (int*)wsb;                  wsb += (size_t)M * 4;
    int* srcC = (int*)wsb;                  wsb += (size_t)M * 4;
    int* dstC = (int*)wsb;                  wsb += (size_t)M * 4;
    int* bsum = (int*)wsb;                  wsb += 64 * 4;
    int* bpre = (int*)wsb;                  wsb += 64 * 4;

    // conditional slot-ordered bf16 rel image (16B-aligned, at the tail)
    size_t used = (size_t)(wsb - (char*)d_ws);
    size_t roff_relbf = (used + 15) & ~(size_t)15;
    bool use_relbf = (roff_relbf + (size_t)M * 128) <= ws_size;
    ushort* relbf = use_relbf ? (ushort*)((char*)d_ws + roff_relbf) : nullptr;

    hipMemsetAsync(cnt, 0, (size_t)N * 4, stream);

    k_prep<<<30, 256, 0, stream>>>(We, Wl, Wr, weTg, wlrTg);
    k_hist<<<1024, 256, 0, stream>>>(dst, cnt, E);
    k_scanA<<<nb, 1024, 0, stream>>>(cnt, bsum, N);
    k_scanB<<<1, 64, 0, stream>>>(bsum, bpre, &roff[N], nb);
    k_scanC<<<nb, 1024, 0, stream>>>(cnt, bpre, roff, wpos, N);
    if (use_relbf) {
        k_scatter2<<<4096, 256, 0, stream>>>(src, dst, wpos, srcC, dstC, rel, relbf, E);
        k_mean<<<2048, 256, 0, stream>>>(roff, relbf, srcC, dstC, N);
    } else {
        k_scatter<<<1024, 256, 0, stream>>>(src, dst, wpos, eidC, srcC, dstC, E);
        k_loopcsr<<<2048, 256, 0, stream>>>(eidC, roff, rel, loopat, eidC, srcC, dstC, N, E);
    }
    k_linC<<<(N + 127) / 128, 512, 0, stream>>>(feat, wlrTg, bl, br, xlbf, xrbf, N);
    if (use_relbf)
        k_fused<true><<<(M + 127) / 128, 512, 0, stream>>>(rel, loopat, relbf, eidC, srcC, dstC,
                                                           xlbf, xrbf, weTg, att, zC, E, M);
    else
        k_fused<false><<<(M + 127) / 128, 512, 0, stream>>>(rel, loopat, relbf, eidC, srcC, dstC,
                                                            xlbf, xrbf, weTg, att, zC, E, M);
    k_agg<<<3200, 256, 0, stream>>>(zC, srcC, roff, xlbf, conv, N);
    k_mlp<<<391, 512, 0, stream>>>(feat, conv, cbias, lng, lnb, ln1g, ln1b, fcw, fcb, fc1w, fc1b,
                                   out, N);
}

// Round 16
// 491.773 us; speedup vs baseline: 1.0261x; 1.0261x over previous
//
#include <hip/hip_runtime.h>
#include <hip/hip_bf16.h>
#include <math.h>

#define LN_EPS 1e-5f
#define NEGS 0.2f

typedef short s8v __attribute__((ext_vector_type(8)));
typedef short s4v __attribute__((ext_vector_type(4)));
typedef float f4v __attribute__((ext_vector_type(4)));
typedef unsigned short ushort;

// ---- helpers ---------------------------------------------------------------
__device__ __forceinline__ float wredsum(float v) {
#pragma unroll
    for (int s = 32; s > 0; s >>= 1) v += __shfl_xor(v, s);
    return v;
}
// fp32 -> bf16 round-to-nearest-even (bit-magic: measured faster than
// __float2bfloat16 library path — R5 236us vs R8 282us on k_fused)
__device__ __forceinline__ ushort f2bf(float x) {
    unsigned int u = __float_as_uint(x);
    u += 0x7fffu + ((u >> 16) & 1u);
    return (ushort)(u >> 16);
}
__device__ __forceinline__ float bf2f(ushort u) {
    return __uint_as_float(((unsigned int)u) << 16);
}

// ---- K_prep: build pre-swizzled bf16 LDS images of We, Wl, Wr --------------
__global__ __launch_bounds__(256) void k_prep(const float* __restrict__ Weg,
                                              const float* __restrict__ Wlg,
                                              const float* __restrict__ Wrg,
                                              ushort* __restrict__ weTg,
                                              ushort* __restrict__ wlrTg) {
    int i = blockIdx.x * 256 + threadIdx.x;
    if (i >= 7680) return;
    int mat = i / 2560;  // 0: We, 1: Wl, 2: Wr
    int j = i - mat * 2560;
    int n = j >> 3, kb = j & 7;
    const float* W = (mat == 0) ? Weg : (mat == 1) ? Wlg : Wrg;
    s8v v;
#pragma unroll
    for (int k = 0; k < 8; k++) v[k] = (short)f2bf(W[(kb * 8 + k) * 320 + n]);
    int by = (n * 128 + kb * 16) ^ ((n & 7) << 4);
    ushort* dstp = (mat == 0) ? weTg : (wlrTg + (mat - 1) * 20480);
    *(s8v*)((char*)dstp + by) = v;
}

// ---- K0: histogram of dst --------------------------------------------------
__global__ void k_hist(const int* __restrict__ dst, int* __restrict__ cnt, int E) {
    int idx = blockIdx.x * blockDim.x + threadIdx.x;
    int stride = gridDim.x * blockDim.x;
    for (; idx < E; idx += stride) atomicAdd(&cnt[dst[idx]], 1);
}

// ---- K0b: 3-phase parallel scan of (cnt[i]+1) -------------------------------
__global__ __launch_bounds__(1024) void k_scanA(const int* __restrict__ cnt,
                                                int* __restrict__ bsum, int N) {
    __shared__ int ws[16];
    int tt = threadIdx.x, ln = tt & 63, wv = tt >> 6;
    int i = blockIdx.x * 1024 + tt;
    int v = (i < N) ? (cnt[i] + 1) : 0;
#pragma unroll
    for (int s = 32; s > 0; s >>= 1) v += __shfl_xor(v, s);
    if (ln == 0) ws[wv] = v;
    __syncthreads();
    if (tt == 0) {
        int s = 0;
#pragma unroll
        for (int k = 0; k < 16; k++) s += ws[k];
        bsum[blockIdx.x] = s;
    }
}
__global__ __launch_bounds__(64) void k_scanB(const int* __restrict__ bsum,
                                              int* __restrict__ bpre,
                                              int* __restrict__ roffN, int nb) {
    int ln = threadIdx.x;
    int v = (ln < nb) ? bsum[ln] : 0;
    int x = v;
#pragma unroll
    for (int off = 1; off < 64; off <<= 1) {
        int y = __shfl_up(x, off);
        if (ln >= off) x += y;
    }
    if (ln < nb) bpre[ln] = x - v;
    if (ln == 63) *roffN = x;
}
__global__ __launch_bounds__(1024) void k_scanC(const int* __restrict__ cnt,
                                                const int* __restrict__ bpre,
                                                int* __restrict__ roff,
                                                int* __restrict__ wpos, int N) {
    __shared__ int ws[16];
    int tt = threadIdx.x, ln = tt & 63, wv = tt >> 6;
    int i = blockIdx.x * 1024 + tt;
    int v = (i < N) ? (cnt[i] + 1) : 0;
    int x = v;
#pragma unroll
    for (int off = 1; off < 64; off <<= 1) {
        int y = __shfl_up(x, off);
        if (ln >= off) x += y;
    }
    if (ln == 63) ws[wv] = x;
    __syncthreads();
    if (wv == 0) {
        int wsv = (ln < 16) ? ws[ln] : 0;
        int xs = wsv;
#pragma unroll
        for (int off = 1; off < 16; off <<= 1) {
            int y = __shfl_up(xs, off);
            if (ln >= off) xs += y;
        }
        if (ln < 16) ws[ln] = xs - wsv;
    }
    __syncthreads();
    int excl = x - v + ws[wv] + bpre[blockIdx.x];
    if (i < N) { roff[i] = excl; wpos[i] = excl; }
}

// ---- K0c (fallback path): scatter edge metadata only -----------------------
__global__ void k_scatter(const int* __restrict__ src, const int* __restrict__ dst,
                          int* __restrict__ wpos, int* __restrict__ eidC,
                          int* __restrict__ srcC, int* __restrict__ dstC, int E) {
    int idx = blockIdx.x * blockDim.x + threadIdx.x;
    int stride = gridDim.x * blockDim.x;
    for (; idx < E; idx += stride) {
        int d = dst[idx];
        int p = atomicAdd(&wpos[d], 1);
        eidC[p] = idx;
        srcC[p] = src[idx];
        dstC[p] = d;
    }
}

// ---- K0c' (relbf path): scatter metadata + rel row -> relbf[slot] ----------
__global__ __launch_bounds__(256) void k_scatter2(const int* __restrict__ src,
                                                  const int* __restrict__ dst,
                                                  int* __restrict__ wpos,
                                                  int* __restrict__ srcC,
                                                  int* __restrict__ dstC,
                                                  const float* __restrict__ rel,
                                                  ushort* __restrict__ relbf, int E) {
    int t = threadIdx.x;
    int ln = t & 63, wv = t >> 6;
    int sub = ln >> 4, m = ln & 15;
    long long base = ((long long)blockIdx.x * 4 + wv) * 4;  // 4 edges/wave
    long long stride = (long long)gridDim.x * 16;
    for (long long e0 = base; e0 < E; e0 += stride) {
        long long e = e0 + sub;
        bool ok = e < E;
        long long ee = ok ? e : (long long)(E - 1);
        float4 v = *(const float4*)(rel + ee * 64 + m * 4);
        int p = 0;
        if (m == 0 && ok) {
            int d = dst[ee];
            p = atomicAdd(&wpos[d], 1);
            srcC[p] = src[ee];
            dstC[p] = d;
        }
        p = __shfl(p, sub * 16);
        if (ok) {
            s4v o;
            o[0] = (short)f2bf(v.x); o[1] = (short)f2bf(v.y);
            o[2] = (short)f2bf(v.z); o[3] = (short)f2bf(v.w);
            *(s4v*)(relbf + (long long)p * 64 + m * 4) = o;
        }
    }
}

// ---- K1' (relbf path): per-node mean from CONTIGUOUS relbf segment ---------
__global__ __launch_bounds__(256) void k_mean(const int* __restrict__ roff,
                                              ushort* __restrict__ relbf,
                                              int* __restrict__ srcC,
                                              int* __restrict__ dstC, int N) {
    int t = threadIdx.x, ln = t & 63, wv = t >> 6;
    int nw = gridDim.x * 4;
    for (int n = blockIdx.x * 4 + wv; n < N; n += nw) {
        int r0 = roff[n], r1 = roff[n + 1];
        int deg = r1 - r0 - 1;  // real edges (last slot = self)
        float s0 = 0.f, s1 = 0.f, s2 = 0.f, s3 = 0.f;
        int j = 0;
        for (; j + 4 <= deg; j += 4) {
            s0 += bf2f(relbf[(long long)(r0 + j) * 64 + ln]);
            s1 += bf2f(relbf[(long long)(r0 + j + 1) * 64 + ln]);
            s2 += bf2f(relbf[(long long)(r0 + j + 2) * 64 + ln]);
            s3 += bf2f(relbf[(long long)(r0 + j + 3) * 64 + ln]);
        }
        for (; j < deg; j++) s0 += bf2f(relbf[(long long)(r0 + j) * 64 + ln]);
        float s = (s0 + s1) + (s2 + s3);
        relbf[(long long)(r1 - 1) * 64 + ln] = f2bf(s / (float)(deg > 0 ? deg : 1));
        if (ln == 0) { srcC[r1 - 1] = n; dstC[r1 - 1] = n; }
    }
}

// ---- K1 (fallback path): loop_attr via CSR gather --------------------------
__global__ __launch_bounds__(256) void k_loopcsr(const int* __restrict__ eidC_ro,
                                                 const int* __restrict__ roff,
                                                 const float* __restrict__ rel,
                                                 float* __restrict__ loopat,
                                                 int* __restrict__ eidC,
                                                 int* __restrict__ srcC,
                                                 int* __restrict__ dstC, int N, int E) {
    int t = threadIdx.x, ln = t & 63, wv = t >> 6;
    int nw = gridDim.x * 4;
    for (int n = blockIdx.x * 4 + wv; n < N; n += nw) {
        int r0 = roff[n], r1 = roff[n + 1];
        int deg = r1 - r0 - 1;
        float s0 = 0.f, s1 = 0.f, s2 = 0.f, s3 = 0.f;
        int j = 0;
        for (; j + 4 <= deg; j += 4) {
            int e0 = eidC_ro[r0 + j], e1 = eidC_ro[r0 + j + 1];
            int e2 = eidC_ro[r0 + j + 2], e3 = eidC_ro[r0 + j + 3];
            s0 += rel[(long long)e0 * 64 + ln];
            s1 += rel[(long long)e1 * 64 + ln];
            s2 += rel[(long long)e2 * 64 + ln];
            s3 += rel[(long long)e3 * 64 + ln];
        }
        for (; j < deg; j++) s0 += rel[(long long)eidC_ro[r0 + j] * 64 + ln];
        float s = (s0 + s1) + (s2 + s3);
        loopat[(long long)n * 64 + ln] = s / (float)(deg > 0 ? deg : 1);
        if (ln == 0) {
            eidC[r1 - 1] = E + n;
            srcC[r1 - 1] = n;
            dstC[r1 - 1] = n;
        }
    }
}

// ---- K2: MFMA linear: xl = bf16(feat@Wl+bl), xr = bf16(feat@Wr+br) ---------
__global__ __launch_bounds__(512) void k_linC(const float* __restrict__ feat,
                                              const ushort* __restrict__ wlrTg,
                                              const float* __restrict__ blg,
                                              const float* __restrict__ brg,
                                              ushort* __restrict__ xlbf,
                                              ushort* __restrict__ xrbf, int N) {
    __shared__ __align__(16) ushort wT[2][64 * 320];  // 80 KB pre-swizzled image
    int t = threadIdx.x;
    {
        const s8v* wsrc = (const s8v*)wlrTg;
        s8v* wdst = (s8v*)&wT[0][0];
        for (int i = t; i < 5120; i += 512) wdst[i] = wsrc[i];  // coalesced copy
    }
    __syncthreads();

    int l = t & 63, wv = t >> 6;
    int g = l >> 4, m = l & 15;
    int wstride = gridDim.x * 128;
    for (int r0 = (blockIdx.x * 8 + wv) * 16; r0 < N; r0 += wstride) {
        s8v afr[2];
        {
            long long row = (r0 + m < N) ? (r0 + m) : (N - 1);
#pragma unroll
            for (int kh = 0; kh < 2; kh++) {
                const float* p = feat + row * 64 + kh * 32 + g * 8;
                float4 u0 = *(const float4*)(p);
                float4 u1 = *(const float4*)(p + 4);
                s8v a;
                a[0] = (short)f2bf(u0.x); a[1] = (short)f2bf(u0.y);
                a[2] = (short)f2bf(u0.z); a[3] = (short)f2bf(u0.w);
                a[4] = (short)f2bf(u1.x); a[5] = (short)f2bf(u1.y);
                a[6] = (short)f2bf(u1.z); a[7] = (short)f2bf(u1.w);
                afr[kh] = a;
            }
        }
#pragma unroll
        for (int mat = 0; mat < 2; mat++) {
            const float* bias = mat ? brg : blg;
            ushort* y = mat ? xrbf : xlbf;
            const char* wb = (const char*)&wT[mat][0];
#pragma unroll
            for (int h = 0; h < 5; h++) {
                f4v acc[4];
#pragma unroll
                for (int ct = 0; ct < 4; ct++) acc[ct] = (f4v)0.0f;
#pragma unroll
                for (int ct = 0; ct < 4; ct++) {
                    int n = h * 64 + ct * 16 + m;
                    int b0 = (n * 128 + 0 * 64 + g * 16) ^ ((n & 7) << 4);
                    int b1 = (n * 128 + 1 * 64 + g * 16) ^ ((n & 7) << 4);
                    s8v bf0 = *(const s8v*)(wb + b0);
                    s8v bf1 = *(const s8v*)(wb + b1);
                    acc[ct] = __builtin_amdgcn_mfma_f32_16x16x32_bf16(afr[0], bf0, acc[ct], 0, 0, 0);
                    acc[ct] = __builtin_amdgcn_mfma_f32_16x16x32_bf16(afr[1], bf1, acc[ct], 0, 0, 0);
                }
                float bv[4];
#pragma unroll
                for (int ct = 0; ct < 4; ct++) bv[ct] = bias[h * 64 + ct * 16 + m];
#pragma unroll
                for (int q = 0; q < 4; q++) {
                    int row = r0 + g * 4 + q;
                    if (row < N) {
                        s4v o;
#pragma unroll
                        for (int ct = 0; ct < 4; ct++) o[ct] = (short)f2bf(acc[ct][q] + bv[ct]);
                        *(s4v*)(y + (long long)row * 320 + h * 64 + m * 4) = o;
                    }
                }
            }
        }
    }
}

// ---- K3: fused em-MFMA + z=exp(logit), CSR slot order (no atomics) ---------
template <bool RELBF>
__global__ __launch_bounds__(512) void k_fused(
    const float* __restrict__ rel, const float* __restrict__ loopat,
    const ushort* __restrict__ relbf,
    const int* __restrict__ eidC, const int* __restrict__ srcC,
    const int* __restrict__ dstC,
    const ushort* __restrict__ xlbf, const ushort* __restrict__ xrbf,
    const ushort* __restrict__ weTg, const float* __restrict__ attg,
    float* __restrict__ zC, int E, int M) {
    __shared__ __align__(16) ushort weT[64 * 320];  // 40 KB pre-swizzled image
    int t = threadIdx.x;
    {
        const s8v* wsrc = (const s8v*)weTg;
        s8v* wdst = (s8v*)weT;
        for (int i = t; i < 2560; i += 512) wdst[i] = wsrc[i];  // coalesced copy
    }
    __syncthreads();

    int l = t & 63, wv = t >> 6;
    int g = l >> 4, m = l & 15;
    int r0 = (blockIdx.x * 8 + wv) * 16;
    if (r0 >= M) return;

    // A fragment: lane holds ea[slot = r0+m][k = kh*32 + g*8 + j]
    s8v afr[2];
    if constexpr (RELBF) {
        int slot = r0 + m;
        if (slot >= M) slot = M - 1;
        const ushort* p = relbf + (long long)slot * 64 + g * 8;
        afr[0] = *(const s8v*)(p);
        afr[1] = *(const s8v*)(p + 32);
    } else {
        int slot = r0 + m;
        if (slot >= M) slot = M - 1;
        int e = eidC[slot];
        const float* ap = (e < E) ? (rel + (long long)e * 64)
                                  : (loopat + (long long)(e - E) * 64);
#pragma unroll
        for (int kh = 0; kh < 2; kh++) {
            const float* p = ap + kh * 32 + g * 8;
            float4 u0 = *(const float4*)(p);
            float4 u1 = *(const float4*)(p + 4);
            s8v a;
            a[0] = (short)f2bf(u0.x); a[1] = (short)f2bf(u0.y);
            a[2] = (short)f2bf(u0.z); a[3] = (short)f2bf(u0.w);
            a[4] = (short)f2bf(u1.x); a[5] = (short)f2bf(u1.y);
            a[6] = (short)f2bf(u1.z); a[7] = (short)f2bf(u1.w);
            afr[kh] = a;
        }
    }

    // epilogue slots for this lane: r0 + g*4 + q
    const ushort* xptr[4];
    const ushort* rptr[4];
    bool vld[4];
    int sarr[4];
#pragma unroll
    for (int q = 0; q < 4; q++) {
        int slot = r0 + g * 4 + q;
        vld[q] = slot < M;
        int ss = vld[q] ? slot : (M - 1);
        sarr[q] = ss;
        int s = srcC[ss], d = dstC[ss];
        xptr[q] = xlbf + (long long)s * 320 + m * 4;
        rptr[q] = xrbf + (long long)d * 320 + m * 4;
    }

    // double-buffered per-head gathers (static indices via full unroll)
    s4v xb[2][4], rb[2][4];
    float attb[2][4];
#pragma unroll
    for (int q = 0; q < 4; q++) {
        xb[0][q] = *(const s4v*)(xptr[q]);
        rb[0][q] = *(const s4v*)(rptr[q]);
    }
#pragma unroll
    for (int ct = 0; ct < 4; ct++) attb[0][ct] = attg[ct * 16 + m];

#pragma unroll
    for (int h = 0; h < 5; h++) {
        if (h < 4) {
#pragma unroll
            for (int q = 0; q < 4; q++) {
                xb[(h + 1) & 1][q] = *(const s4v*)(xptr[q] + (h + 1) * 64);
                rb[(h + 1) & 1][q] = *(const s4v*)(rptr[q] + (h + 1) * 64);
            }
#pragma unroll
            for (int ct = 0; ct < 4; ct++)
                attb[(h + 1) & 1][ct] = attg[(h + 1) * 64 + ct * 16 + m];
        }

        f4v acc[4];
#pragma unroll
        for (int ct = 0; ct < 4; ct++) acc[ct] = (f4v)0.0f;
        __builtin_amdgcn_s_setprio(1);
#pragma unroll
        for (int ct = 0; ct < 4; ct++) {
            int n = h * 64 + ct * 16 + m;
            int b0 = (n * 128 + 0 * 64 + g * 16) ^ ((n & 7) << 4);
            int b1 = (n * 128 + 1 * 64 + g * 16) ^ ((n & 7) << 4);
            s8v bf0 = *(const s8v*)((const char*)weT + b0);
            s8v bf1 = *(const s8v*)((const char*)weT + b1);
            acc[ct] = __builtin_amdgcn_mfma_f32_16x16x32_bf16(afr[0], bf0, acc[ct], 0, 0, 0);
            acc[ct] = __builtin_amdgcn_mfma_f32_16x16x32_bf16(afr[1], bf1, acc[ct], 0, 0, 0);
        }
        __builtin_amdgcn_s_setprio(0);

#pragma unroll
        for (int q = 0; q < 4; q++) {
            float sum = 0.f;
#pragma unroll
            for (int ct = 0; ct < 4; ct++) {
                float v = acc[ct][q] + bf2f((ushort)xb[h & 1][q][ct])
                                     + bf2f((ushort)rb[h & 1][q][ct]);
                // leaky(v) = 0.6v + 0.4|v|  (|.| is a free VOP3 modifier)
                float lv = fmaf(0.4f, fabsf(v), 0.6f * v);
                sum = fmaf(lv, attb[h & 1][ct], sum);
            }
            sum += __shfl_xor(sum, 1);
            sum += __shfl_xor(sum, 2);
            sum += __shfl_xor(sum, 4);
            sum += __shfl_xor(sum, 8);
            if (vld[q] && m == 0)
                zC[(long long)sarr[q] * 5 + h] = __expf(sum);  // logits small; no max-shift
        }
    }
}

// ---- K4: single-pass conv accumulation (den folded into the same loop) -----
__global__ __launch_bounds__(256) void k_agg(const float* __restrict__ zC,
                                             const int* __restrict__ srcC,
                                             const int* __restrict__ roff,
                                             const ushort* __restrict__ xlbf,
                                             float* __restrict__ conv, int N) {
    int t = threadIdx.x, ln = t & 63, wv = t >> 6;
    int sub = ln >> 4, m = ln & 15;
    int nw = gridDim.x * 4;
    for (int n = blockIdx.x * 4 + wv; n < N; n += nw) {
        int r0 = roff[n], r1 = roff[n + 1];
        int deg = r1 - r0;  // includes self slot
        float se[5] = {0.f, 0.f, 0.f, 0.f, 0.f};
        float accv[5][4];
#pragma unroll
        for (int h = 0; h < 5; h++)
#pragma unroll
            for (int j = 0; j < 4; j++) accv[h][j] = 0.f;
        for (int jj = sub; jj < deg; jj += 4) {
            int slot = r0 + jj;
            int s = srcC[slot];
            const ushort* xp = xlbf + (long long)s * 320 + m * 4;
            long long lb = (long long)slot * 5;
#pragma unroll
            for (int h = 0; h < 5; h++) {
                float z = zC[lb + h];
                se[h] += z;
                s4v xv = *(const s4v*)(xp + h * 64);
#pragma unroll
                for (int j = 0; j < 4; j++)
                    accv[h][j] = fmaf(z, bf2f((ushort)xv[j]), accv[h][j]);
            }
        }
        // each z was added by all 16 m-lanes of its sub-group -> divide by 16
        float dh[5];
#pragma unroll
        for (int h = 0; h < 5; h++) dh[h] = 16.0f / wredsum(se[h]);
        float tot[4];
#pragma unroll
        for (int j = 0; j < 4; j++) {
            float v = 0.f;
#pragma unroll
            for (int h = 0; h < 5; h++) v = fmaf(accv[h][j], dh[h], v);
            v += __shfl_xor(v, 16);
            v += __shfl_xor(v, 32);
            tot[j] = v;
        }
        float v0 = __shfl(tot[0], m);
        float v1 = __shfl(tot[1], m);
        float v2 = __shfl(tot[2], m);
        float v3 = __shfl(tot[3], m);
        float outv = (sub == 0) ? v0 : (sub == 1) ? v1 : (sub == 2) ? v2 : v3;
        conv[(long long)n * 64 + ln] = outv * 0.2f;
    }
}

// ---- K5: residual + LN -> MFMA MLP(64->128->64) -> residual + LN -----------
__global__ __launch_bounds__(512) void k_mlp(const float* __restrict__ feat,
                                             const float* __restrict__ conv,
                                             const float* __restrict__ cbias,
                                             const float* __restrict__ lng,
                                             const float* __restrict__ lnb,
                                             const float* __restrict__ ln1g,
                                             const float* __restrict__ ln1b,
                                             const float* __restrict__ fcwg,
                                             const float* __restrict__ fcb,
                                             const float* __restrict__ fc1wg,
                                             const float* __restrict__ fc1b,
                                             float* __restrict__ out, int N) {
    __shared__ __align__(16) ushort w1T[64 * 128];
    __shared__ __align__(16) ushort w2T[64 * 128];
    __shared__ __align__(16) ushort tls[8][16 * 128];
    __shared__ __align__(16) ushort xnl[8][16 * 64];
    int t = threadIdx.x;
    for (int i = t; i < 8192; i += 512) {
        int k = i >> 7, n = i & 127;
        int by = (n * 128 + k * 2) ^ ((n & 7) << 4);
        w1T[by >> 1] = f2bf(fcwg[i]);
    }
    for (int i = t; i < 8192; i += 512) {
        int k = i >> 6, n = i & 63;
        int by = (n * 256 + k * 2) ^ ((n & 7) << 4);
        w2T[by >> 1] = f2bf(fc1wg[i]);
    }
    __syncthreads();
    int ln = t & 63, wv = t >> 6;
    int g = ln >> 4, m = ln & 15;
    char* tb = (char*)&tls[wv][0];
    char* xb = (char*)&xnl[wv][0];
    float fcbv[8];
#pragma unroll
    for (int ct = 0; ct < 8; ct++) fcbv[ct] = fcb[ct * 16 + m];
    float fc1bv[4], g1v[4], b1v[4];
#pragma unroll
    for (int ct = 0; ct < 4; ct++) {
        fc1bv[ct] = fc1b[ct * 16 + m];
        g1v[ct] = ln1g[ct * 16 + m];
        b1v[ct] = ln1b[ct * 16 + m];
    }
    int nblk = gridDim.x * 8;
    for (int nb0 = (blockIdx.x * 8 + wv) * 16; nb0 < N; nb0 += nblk * 16) {
        int node = nb0 + m;
        long long nd = (node < N) ? node : (N - 1);
        float xv[2][8];
#pragma unroll
        for (int kh = 0; kh < 2; kh++) {
            int c0 = kh * 32 + g * 8;
            const float* fp = feat + nd * 64 + c0;
            const float* cp = conv + nd * 64 + c0;
            float4 f0 = *(const float4*)fp, f1 = *(const float4*)(fp + 4);
            float4 q0 = *(const float4*)cp, q1 = *(const float4*)(cp + 4);
            float4 cb0 = *(const float4*)(cbias + c0), cb1 = *(const float4*)(cbias + c0 + 4);
            xv[kh][0] = f0.x + q0.x + cb0.x; xv[kh][1] = f0.y + q0.y + cb0.y;
            xv[kh][2] = f0.z + q0.z + cb0.z; xv[kh][3] = f0.w + q0.w + cb0.w;
            xv[kh][4] = f1.x + q1.x + cb1.x; xv[kh][5] = f1.y + q1.y + cb1.y;
            xv[kh][6] = f1.z + q1.z + cb1.z; xv[kh][7] = f1.w + q1.w + cb1.w;
        }
        float sm = 0.f;
#pragma unroll
        for (int kh = 0; kh < 2; kh++)
#pragma unroll
            for (int j = 0; j < 8; j++) sm += xv[kh][j];
        sm += __shfl_xor(sm, 16); sm += __shfl_xor(sm, 32);
        float mu = sm * (1.0f / 64.0f);
        float vr = 0.f;
#pragma unroll
        for (int kh = 0; kh < 2; kh++)
#pragma unroll
            for (int j = 0; j < 8; j++) {
                float dv = xv[kh][j] - mu;
                vr += dv * dv;
            }
        vr += __shfl_xor(vr, 16); vr += __shfl_xor(vr, 32);
        float rs = rsqrtf(vr * (1.0f / 64.0f) + LN_EPS);
        s8v af[2];
#pragma unroll
        for (int kh = 0; kh < 2; kh++) {
            int c0 = kh * 32 + g * 8;
            float4 g0 = *(const float4*)(lng + c0), g1 = *(const float4*)(lng + c0 + 4);
            float4 e0 = *(const float4*)(lnb + c0), e1 = *(const float4*)(lnb + c0 + 4);
            float gg[8] = {g0.x, g0.y, g0.z, g0.w, g1.x, g1.y, g1.z, g1.w};
            float bb[8] = {e0.x, e0.y, e0.z, e0.w, e1.x, e1.y, e1.z, e1.w};
#pragma unroll
            for (int j = 0; j < 8; j++)
                af[kh][j] = (short)f2bf((xv[kh][j] - mu) * rs * gg[j] + bb[j]);
            int by = (m * 128 + (kh * 32 + g * 8) * 2) ^ ((m & 7) << 4);
            *(s8v*)(xb + by) = af[kh];
        }
        f4v a1[8];
#pragma unroll
        for (int ct = 0; ct < 8; ct++) a1[ct] = (f4v)0.0f;
#pragma unroll
        for (int ct = 0; ct < 8; ct++) {
            int n1 = ct * 16 + m;
#pragma unroll
            for (int kh = 0; kh < 2; kh++) {
                int by = (n1 * 128 + (kh * 32 + g * 8) * 2) ^ ((n1 & 7) << 4);
                s8v bf = *(const s8v*)((const char*)w1T + by);
                a1[ct] = __builtin_amdgcn_mfma_f32_16x16x32_bf16(af[kh], bf, a1[ct], 0, 0, 0);
            }
        }
#pragma unroll
        for (int ct = 0; ct < 8; ct++)
#pragma unroll
            for (int q = 0; q < 4; q++) {
                int r = g * 4 + q, c = ct * 16 + m;
                int by = (r * 256 + c * 2) ^ ((r & 7) << 4);
                *(ushort*)(tb + by) = f2bf(a1[ct][q] + fcbv[ct]);
            }
        f4v a2[4];
#pragma unroll
        for (int ct = 0; ct < 4; ct++) a2[ct] = (f4v)0.0f;
#pragma unroll
        for (int kh2 = 0; kh2 < 4; kh2++) {
            int by = (m * 256 + (kh2 * 32 + g * 8) * 2) ^ ((m & 7) << 4);
            s8v a2f = *(const s8v*)(tb + by);
#pragma unroll
            for (int ct = 0; ct < 4; ct++) {
                int n2 = ct * 16 + m;
                int by2 = (n2 * 256 + (kh2 * 32 + g * 8) * 2) ^ ((n2 & 7) << 4);
                s8v bf = *(const s8v*)((const char*)w2T + by2);
                a2[ct] = __builtin_amdgcn_mfma_f32_16x16x32_bf16(a2f, bf, a2[ct], 0, 0, 0);
            }
        }
#pragma unroll
        for (int q = 0; q < 4; q++) {
            int r = g * 4 + q;
            float yv[4];
#pragma unroll
            for (int ct = 0; ct < 4; ct++) {
                int by = (r * 128 + (ct * 16 + m) * 2) ^ ((r & 7) << 4);
                yv[ct] = bf2f(*(const ushort*)(xb + by)) + a2[ct][q] + fc1bv[ct];
            }
            float sm2 = (yv[0] + yv[1]) + (yv[2] + yv[3]);
            sm2 += __shfl_xor(sm2, 1); sm2 += __shfl_xor(sm2, 2);
            sm2 += __shfl_xor(sm2, 4); sm2 += __shfl_xor(sm2, 8);
            float mu2 = sm2 * (1.0f / 64.0f);
            float vr2 = 0.f;
#pragma unroll
            for (int ct = 0; ct < 4; ct++) {
                float dv = yv[ct] - mu2;
                vr2 += dv * dv;
            }
            vr2 += __shfl_xor(vr2, 1); vr2 += __shfl_xor(vr2, 2);
            vr2 += __shfl_xor(vr2, 4); vr2 += __shfl_xor(vr2, 8);
            float rs2 = rsqrtf(vr2 * (1.0f / 64.0f) + LN_EPS);
            int rn = nb0 + r;
            if (rn < N) {
#pragma unroll
                for (int ct = 0; ct < 4; ct++)
                    out[(long long)rn * 64 + ct * 16 + m] =
                        (yv[ct] - mu2) * rs2 * g1v[ct] + b1v[ct];
            }
        }
    }
}

// ---- launch ----------------------------------------------------------------
extern "C" void kernel_launch(void* const* d_in, const int* in_sizes, int n_in,
                              void* d_out, int out_size, void* d_ws, size_t ws_size,
                              hipStream_t stream) {
    const float* feat = (const float*)d_in[0];
    const int* ei = (const int*)d_in[1];
    const float* rel = (const float*)d_in[2];
    const float* Wl = (const float*)d_in[3];
    const float* bl = (const float*)d_in[4];
    const float* Wr = (const float*)d_in[5];
    const float* br = (const float*)d_in[6];
    const float* We = (const float*)d_in[7];
    const float* att = (const float*)d_in[8];
    const float* cbias = (const float*)d_in[9];
    const float* lng = (const float*)d_in[10];
    const float* lnb = (const float*)d_in[11];
    const float* ln1g = (const float*)d_in[12];
    const float* ln1b = (const float*)d_in[13];
    const float* fcw = (const float*)d_in[14];
    const float* fcb = (const float*)d_in[15];
    const float* fc1w = (const float*)d_in[16];
    const float* fc1b = (const float*)d_in[17];
    float* out = (float*)d_out;

    int N = in_sizes[0] / 64;
    int E = in_sizes[1] / 2;
    int M = E + N;
    const int* src = ei;
    const int* dst = ei + E;
    int nb = (N + 1023) / 1024;

    char* wsb = (char*)d_ws;
    ushort* xlbf = (ushort*)wsb;            wsb += (size_t)N * 320 * 2;
    ushort* xrbf = (ushort*)wsb;            wsb += (size_t)N * 320 * 2;
    float* loopat = (float*)wsb;            wsb += (size_t)N * 64 * 4;
    float* conv = (float*)wsb;              wsb += (size_t)N * 64 * 4;
    ushort* weTg = (ushort*)wsb;            wsb += 40960;
    ushort* wlrTg = (ushort*)wsb;           wsb += 81920;
    float* zC = (float*)wsb;                wsb += (size_t)M * 5 * 4;
    int* cnt = (int*)wsb;                   wsb += (size_t)N * 4;
    int* roff = (int*)wsb;                  wsb += (size_t)(N + 1) * 4;
    int* wpos = (int*)wsb;                  wsb += (size_t)N * 4;
    int* eidC = (int*)wsb;                  wsb += (size_t)M * 4;
    int* srcC = (int*)wsb;                  wsb += (size_t)M * 4;
    int* dstC = (int*)wsb;                  wsb += (size_t)M * 4;
    int* bsum = (int*)wsb;                  wsb += 64 * 4;
    int* bpre = (int*)wsb;                  wsb += 64 * 4;

    // conditional slot-ordered bf16 rel image (16B-aligned, at the tail)
    size_t used = (size_t)(wsb - (char*)d_ws);
    size_t roff_relbf = (used + 15) & ~(size_t)15;
    bool use_relbf = (roff_relbf + (size_t)M * 128) <= ws_size;
    ushort* relbf = use_relbf ? (ushort*)((char*)d_ws + roff_relbf) : nullptr;

    hipMemsetAsync(cnt, 0, (size_t)N * 4, stream);

    k_prep<<<30, 256, 0, stream>>>(We, Wl, Wr, weTg, wlrTg);
    k_hist<<<1024, 256, 0, stream>>>(dst, cnt, E);
    k_scanA<<<nb, 1024, 0, stream>>>(cnt, bsum, N);
    k_scanB<<<1, 64, 0, stream>>>(bsum, bpre, &roff[N], nb);
    k_scanC<<<nb, 1024, 0, stream>>>(cnt, bpre, roff, wpos, N);
    if (use_relbf) {
        k_scatter2<<<4096, 256, 0, stream>>>(src, dst, wpos, srcC, dstC, rel, relbf, E);
        k_mean<<<2048, 256, 0, stream>>>(roff, relbf, srcC, dstC, N);
    } else {
        k_scatter<<<1024, 256, 0, stream>>>(src, dst, wpos, eidC, srcC, dstC, E);
        k_loopcsr<<<2048, 256, 0, stream>>>(eidC, roff, rel, loopat, eidC, srcC, dstC, N, E);
    }
    k_linC<<<(N + 127) / 128, 512, 0, stream>>>(feat, wlrTg, bl, br, xlbf, xrbf, N);
    if (use_relbf)
        k_fused<true><<<(M + 127) / 128, 512, 0, stream>>>(rel, loopat, relbf, eidC, srcC, dstC,
                                                           xlbf, xrbf, weTg, att, zC, E, M);
    else
        k_fused<false><<<(M + 127) / 128, 512, 0, stream>>>(rel, loopat, relbf, eidC, srcC, dstC,
                                                            xlbf, xrbf, weTg, att, zC, E, M);
    k_agg<<<3200, 256, 0, stream>>>(zC, srcC, roff, xlbf, conv, N);
    k_mlp<<<391, 512, 0, stream>>>(feat, conv, cbias, lng, lnb, ln1g, ln1b, fcw, fcb, fc1w, fc1b,
                                   out, N);
}